// Round 7
// baseline (3169.111 us; speedup 1.0000x reference)
//
#include <hip/hip_runtime.h>
#include <cstdint>
#include <cstddef>

#define B_  512
#define L_  60
#define D_  300
#define H_  256
#define BT  1024
#define KX  320
#define KL  576
#define NG  1024

typedef _Float16 half8   __attribute__((ext_vector_type(8)));
typedef _Float16 half4_t __attribute__((ext_vector_type(4)));
typedef float    floatx4 __attribute__((ext_vector_type(4)));

__device__ __forceinline__ float fast_tanh(float x){ float e = __expf(2.f*x); return 1.f - 2.f/(e + 1.f); }
__device__ __forceinline__ float sigm(float x){ return 1.f/(1.f + __expf(-x)); }

#define MFMA16(a,b,c) __builtin_amdgcn_mfma_f32_16x16x32_f16(a,b,c,0,0,0)

// light barrier: ordering only; h data travels via agent-scope (IF$) atomics.
__device__ __forceinline__ void sync_group(int* slot, int nexp)
{
    __syncthreads();
    if (threadIdx.x == 0) {
        int prev = __hip_atomic_fetch_add(slot, 1, __ATOMIC_RELAXED, __HIP_MEMORY_SCOPE_AGENT);
        if (prev == nexp - 1) {
            __hip_atomic_store(slot + 1, 1, __ATOMIC_RELAXED, __HIP_MEMORY_SCOPE_AGENT);
        } else {
            while (!__hip_atomic_load(slot + 1, __ATOMIC_RELAXED, __HIP_MEMORY_SCOPE_AGENT))
                __builtin_amdgcn_s_sleep(1);
        }
    }
    __syncthreads();
}

// ================= k_prep: gather X, transpose weights, zero barriers =================
__global__ __launch_bounds__(256) void k_prep(const float* __restrict__ E,
    const float* __restrict__ Wx1, const float* __restrict__ Wh1,
    const float* __restrict__ Wx2, const float* __restrict__ Wh2,
    const float* __restrict__ W_y, const float* __restrict__ Wh_a, const float* __restrict__ Wr_a,
    const float* __restrict__ Wt_a, const float* __restrict__ Wp_a, const float* __restrict__ Wxa,
    const int* __restrict__ in1, const int* __restrict__ in2,
    _Float16* __restrict__ X16, _Float16* __restrict__ BcatT, _Float16* __restrict__ AW,
    int* __restrict__ bar)
{
    const int tid = threadIdx.x, bid = blockIdx.x;
    int g0 = bid*256 + tid;
    if (g0 < 3840) bar[g0] = 0;

    for (int it = 0; it < 19; ++it) {
        int gid = it*131072 + g0;
        if (gid < 2457600) {
            int row = gid / (L_*40);
            int rem = gid - row*(L_*40);
            int t  = rem / 40;
            int ch = rem - t*40;
            int k0 = ch*8;
            int tok = (row < B_) ? in1[row*L_ + t] : in2[(row - B_)*L_ + t];
            const float* src = E + (size_t)tok*D_ + k0;
            half8 o;
            #pragma unroll
            for (int k = 0; k < 8; ++k) o[k] = (_Float16)0.f;
            if (k0 + 8 <= D_) {
                float4 a = *(const float4*)(src);
                float4 b = *(const float4*)(src + 4);
                o[0]=(_Float16)a.x; o[1]=(_Float16)a.y; o[2]=(_Float16)a.z; o[3]=(_Float16)a.w;
                o[4]=(_Float16)b.x; o[5]=(_Float16)b.y; o[6]=(_Float16)b.z; o[7]=(_Float16)b.w;
            } else if (k0 < D_) {
                float4 a = *(const float4*)(src);
                o[0]=(_Float16)a.x; o[1]=(_Float16)a.y; o[2]=(_Float16)a.z; o[3]=(_Float16)a.w;
            }
            *(half8*)(X16 + ((size_t)row*L_ + t)*KX + k0) = o;
        }
    }
    for (int it = 0; it < 9; ++it) {
        int idx = it*131072 + g0;                 // 9*131072 == 2*KL*NG exactly
        int set = (idx >= KL*NG) ? 1 : 0;
        int rem = idx - set*(KL*NG);
        int k = rem >> 10, n = rem & 1023;
        const float* Wx = set ? Wx2 : Wx1;
        const float* Wh = set ? Wh2 : Wh1;
        float v = 0.f;
        if (k < D_)       v = Wx[k*NG + n];
        else if (k >= KX) v = Wh[(k - KX)*NG + n];
        BcatT[((size_t)set*NG + n)*KL + k] = (_Float16)v;
    }
    for (int it = 0; it < 4; ++it) {
        int idx = it*131072 + g0;
        if (idx < 458752) {
            float v; int dst;
            if (idx < 65536) {
                int k = idx >> 8, n = idx & 255;
                v = W_y[k*256 + n];
                dst = n*256 + k;
            } else if (idx < 131072) {
                int j = idx - 65536; int k = j >> 8, n = j & 255;
                v = Wh_a[k*256 + n];
                dst = 65536 + n*256 + k;
            } else if (idx < 262144) {
                int j = idx - 131072; int n = j >> 8, k = j & 255;
                v = (n < 256) ? Wr_a[k*256 + n] : Wt_a[k*256 + (n - 256)];
                dst = 131072 + n*256 + k;
            } else {
                int j = idx - 262144; int n = j >> 9, k = j & 511;
                v = (k < 256) ? Wp_a[k*256 + n] : Wxa[(k - 256)*256 + n];
                dst = 262144 + n*512 + k;
            }
            AW[dst] = (_Float16)v;
        }
    }
}

// ================= k_lstm: persistent, 512 blocks, 59 light group barriers =================
// block (ht, mt): 64 rows x 16 h-dims (64 gate cols), K=576 split across wave pairs.
// h exchanged via agent-scope (IF$) atomics; all 8 h-chunks prefetched at step start.
__global__ __launch_bounds__(256, 2) void k_lstm(
    const _Float16* __restrict__ X16, const _Float16* __restrict__ BcatT,
    const float* __restrict__ b1, const float* __restrict__ b2,
    const int* __restrict__ s1, const int* __restrict__ s2,
    _Float16* __restrict__ Y16, _Float16* __restrict__ h16, int* __restrict__ bar)
{
    __shared__ float sG[2][64][65];            // aliases sA
    _Float16* sA = (_Float16*)sG;

    const int tid = threadIdx.x, bid = blockIdx.x;
    const int lane = tid & 63, wv = tid >> 6;
    const int q = lane >> 4, lm = lane & 15;
    const int ht = bid & 15, mt = bid >> 4;
    const int set = mt >> 4;
    const int m0 = mt*64;
    const int kh = wv >> 1;
    const int wn = (wv & 1)*32;
    const int cb = wn >> 4;

    half8 bfr[9][2];
    #pragma unroll
    for (int ch = 0; ch < 9; ++ch)
        #pragma unroll
        for (int ti = 0; ti < 2; ++ti)
            bfr[ch][ti] = *(const half8*)(BcatT +
                ((size_t)set*NG + (cb+ti)*256 + ht*16 + lm)*KL + kh*288 + ch*32 + q*8);

    const int amA = tid >> 2, kgA = (tid & 3)*8;
    const int rsA = (m0 + amA) & 1023;
    const int xrowA = set ? ((rsA + 512) & 1023) : rsA;

    const float* bias = set ? b2 : b1;
    const int pc = tid & 7;
    const int eh = ht*16 + pc*2;
    float bI[2], bJ[2], bF[2], bO[2];
    #pragma unroll
    for (int j = 0; j < 2; ++j) {
        bI[j] = bias[eh + j]; bJ[j] = bias[256 + eh + j];
        bF[j] = bias[512 + eh + j]; bO[j] = bias[768 + eh + j];
    }
    int esl[2]; float c_st[2][2], h_st[2][2];
    #pragma unroll
    for (int rp = 0; rp < 2; ++rp) {
        int rs = (m0 + (tid >> 3) + rp*32) & 1023;
        esl[rp] = (set == 0) ? ((rs < B_) ? s1[rs] : s2[rs - B_])
                             : ((rs < B_) ? s2[rs] : s1[rs - B_]);
        c_st[rp][0] = 0.f; c_st[rp][1] = 0.f;
        h_st[rp][0] = 0.f; h_st[rp][1] = 0.f;
    }

    half8 zero8;
    #pragma unroll
    for (int k = 0; k < 8; ++k) zero8[k] = (_Float16)0.f;

    for (int t = 0; t < L_; ++t) {
        const int p_in = t & 1, p_out = (t + 1) & 1;
        const _Float16* hin  = h16 + (size_t)(set*2 + p_in)*BT*H_;
        _Float16*       hout = h16 + (size_t)(set*2 + p_out)*BT*H_;
        const _Float16* aX = X16 + ((size_t)xrowA*L_ + t)*KX;
        const _Float16* aH = hin + (size_t)rsA*H_;

        // deep prefetch: all 8 h-chunks for this thread's staging slot (IF$-coherent)
        half8 hreg[8];
        if (t > 0) {
            #pragma unroll
            for (int j = 0; j < 8; ++j) {
                union { unsigned long long u[2]; half8 v; } cv;
                const _Float16* hp = aH + j*32 + kgA;
                cv.u[0] = __hip_atomic_load((const unsigned long long*)(hp),
                                            __ATOMIC_RELAXED, __HIP_MEMORY_SCOPE_AGENT);
                cv.u[1] = __hip_atomic_load((const unsigned long long*)(hp + 4),
                                            __ATOMIC_RELAXED, __HIP_MEMORY_SCOPE_AGENT);
                hreg[j] = cv.v;
            }
        } else {
            #pragma unroll
            for (int j = 0; j < 8; ++j) hreg[j] = zero8;
        }

        floatx4 acc[4][2];
        #pragma unroll
        for (int mi = 0; mi < 4; ++mi)
            #pragma unroll
            for (int ti = 0; ti < 2; ++ti) acc[mi][ti] = (floatx4){0.f,0.f,0.f,0.f};

        half8 av0 = *(const half8*)(aX + kgA);
        half8 av1f = *(const half8*)(aX + 288 + kgA);   // chunk 0 of K-half1 is always x

        #pragma unroll
        for (int i = 0; i < 9; ++i) {
            __syncthreads();
            *(half8*)(sA + (     amA)*40 + kgA) = av0;
            *(half8*)(sA + (64 + amA)*40 + kgA) = (i == 0) ? av1f : hreg[i-1];
            __syncthreads();
            if (i < 8) av0 = *(const half8*)(aX + (i+1)*32 + kgA);
            half8 af[4];
            #pragma unroll
            for (int mi = 0; mi < 4; ++mi)
                af[mi] = *(const half8*)(sA + (kh*64 + mi*16 + lm)*40 + q*8);
            #pragma unroll
            for (int mi = 0; mi < 4; ++mi) {
                acc[mi][0] = MFMA16(af[mi], bfr[i][0], acc[mi][0]);
                acc[mi][1] = MFMA16(af[mi], bfr[i][1], acc[mi][1]);
            }
        }

        __syncthreads();
        #pragma unroll
        for (int mi = 0; mi < 4; ++mi)
            #pragma unroll
            for (int ti = 0; ti < 2; ++ti)
                #pragma unroll
                for (int r = 0; r < 4; ++r)
                    sG[kh][mi*16 + q*4 + r][wn + ti*16 + lm] = acc[mi][ti][r];
        __syncthreads();

        #pragma unroll
        for (int rp = 0; rp < 2; ++rp) {
            int row = (tid >> 3) + rp*32;
            int gr = m0 + row;
            int rs = gr & 1023;
            bool act = (t < esl[rp]);
            union { _Float16 h[2]; uint32_t u; } hp, yp;
            #pragma unroll
            for (int j = 0; j < 2; ++j) {
                int hh = pc*2 + j;
                float gi = sG[0][row][     hh] + sG[1][row][     hh] + bI[j];
                float gj = sG[0][row][16 + hh] + sG[1][row][16 + hh] + bJ[j];
                float gf = sG[0][row][32 + hh] + sG[1][row][32 + hh] + bF[j];
                float go = sG[0][row][48 + hh] + sG[1][row][48 + hh] + bO[j];
                float c_new = c_st[rp][j]*sigm(gf + 1.f) + sigm(gi)*fast_tanh(gj);
                float h_new = fast_tanh(c_new)*sigm(go);
                if (act) { c_st[rp][j] = c_new; h_st[rp][j] = h_new; }
                hp.h[j] = (_Float16)h_st[rp][j];
                yp.h[j] = act ? (_Float16)h_new : (_Float16)0.f;
            }
            __hip_atomic_store((uint32_t*)(hout + (size_t)rs*H_ + eh), hp.u,
                               __ATOMIC_RELAXED, __HIP_MEMORY_SCOPE_AGENT);
            *(uint32_t*)(Y16 + ((size_t)gr*L_ + t)*H_ + eh) = yp.u;
        }
        if (t < L_ - 1)
            sync_group(bar + (t*32 + mt)*2, 16);
    }
}

// ================= k_wyyth: WyY (z=0) / TH (z=1), B cached in LDS =================
__global__ __launch_bounds__(256) void k_wyyth(const _Float16* __restrict__ Y16,
    const _Float16* __restrict__ AW, _Float16* __restrict__ WyY16, _Float16* __restrict__ TH16)
{
    __shared__ _Float16 sB[64*264];
    const int tid = threadIdx.x, bid = blockIdx.x;
    const int lane = tid & 63, wv = tid >> 6;
    const int q = lane >> 4, lm = lane & 15;
    const int slot = bid & 7;
    const int z = slot >> 2, nt = slot & 3;
    const int n0 = nt*64;
    {
        int rowB = tid >> 2;
        int kb = (tid & 3)*64;
        #pragma unroll
        for (int s = 0; s < 8; ++s)
            *(half8*)(sB + rowB*264 + kb + s*8) =
                *(const half8*)(AW + (size_t)z*65536 + (size_t)(n0 + rowB)*H_ + kb + s*8);
    }
    __syncthreads();
    const _Float16* Ybase = Y16 + (size_t)z*((size_t)BT*L_*H_);
    _Float16* dst = z ? TH16 : WyY16;
    for (int mi_ = 0; mi_ < 15; ++mi_) {
        int m0w = ((bid >> 3) + mi_*64)*64;
        floatx4 acc[4];
        #pragma unroll
        for (int ti = 0; ti < 4; ++ti) acc[ti] = (floatx4){0.f,0.f,0.f,0.f};
        const _Float16* aRow = Ybase + (size_t)(m0w + wv*16 + lm)*H_ + q*8;
        #pragma unroll
        for (int ch = 0; ch < 8; ++ch) {
            half8 a = *(const half8*)(aRow + ch*32);
            #pragma unroll
            for (int ti = 0; ti < 4; ++ti) {
                half8 b = *(const half8*)(sB + (ti*16 + lm)*264 + ch*32 + q*8);
                acc[ti] = MFMA16(a, b, acc[ti]);
            }
        }
        #pragma unroll
        for (int ti = 0; ti < 4; ++ti)
            #pragma unroll
            for (int r = 0; r < 4; ++r)
                dst[(size_t)(m0w + wv*16 + q*4 + r)*H_ + n0 + ti*16 + lm] = (_Float16)acc[ti][r];
    }
}

// ================= k_attn: 1024 blocks x 1 row, persistent over t, no inter-block comm =================
__global__ __launch_bounds__(256, 2) void k_attn(
    const _Float16* __restrict__ Y16, const _Float16* __restrict__ WyY16,
    const _Float16* __restrict__ TH16, const _Float16* __restrict__ AW,
    const float* __restrict__ w_a, _Float16* __restrict__ rL16,
    const int* __restrict__ s1, const int* __restrict__ s2)
{
    __shared__ _Float16 sR[16*264];    // only row 0 live; rows 1-15 zero (MFMA A-frag)
    __shared__ float sW[520];
    __shared__ float sTW[264];
    __shared__ float sLog[64];
    __shared__ float sAl[64];
    __shared__ float sWa[256];

    const int tid = threadIdx.x, u = blockIdx.x;
    const int lane = tid & 63, wv = tid >> 6;
    const int q = lane >> 4, lm = lane & 15;

    const int sCap = (u < B_) ? s2[u] : s1[u - B_];
    const int sa   = (u < B_) ? s1[u] : s2[u - B_];

    sWa[tid] = w_a[tid];
    for (int i = tid; i < 16*264; i += 256) sR[i] = (_Float16)0.f;
    __syncthreads();

    const _Float16* WrtT = AW + 131072;
    const int lsub = lane >> 2, li = lane & 3;

    for (int t = 0; t < sCap; ++t) {
        __syncthreads();   // sR stable from previous step
        if (t > 0) {
            floatx4 acc[8];
            #pragma unroll
            for (int i = 0; i < 8; ++i) acc[i] = (floatx4){0.f,0.f,0.f,0.f};
            #pragma unroll
            for (int ch = 0; ch < 8; ++ch) {
                half8 a = *(const half8*)(sR + lm*264 + ch*32 + q*8);
                #pragma unroll
                for (int ti = 0; ti < 8; ++ti) {
                    half8 b = *(const half8*)(WrtT + (size_t)(wv*128 + ti*16 + lm)*256 + ch*32 + q*8);
                    acc[ti] = MFMA16(a, b, acc[ti]);
                }
            }
            if (q == 0) {
                #pragma unroll
                for (int ti = 0; ti < 8; ++ti)
                    sW[wv*128 + ti*16 + lm] = acc[ti][0];   // row 0 only
            }
        } else {
            for (int i = tid; i < 520; i += 256) sW[i] = 0.f;
        }
        __syncthreads();
        sTW[tid] = (float)TH16[((size_t)u*L_ + t)*H_ + tid] + sW[tid];
        __syncthreads();

        // logits: 64 l-slots in one pass (l = wv*16 + lsub), quad covers h
        {
            int l = wv*16 + lsub;
            float v = 0.f;
            if (l < sa) {
                const _Float16* wy = WyY16 + ((size_t)u*L_ + l)*H_;
                #pragma unroll
                for (int j = 0; j < 16; ++j) {
                    int h0 = j*16 + li*4;
                    half4_t yv = *(const half4_t*)(wy + h0);
                    #pragma unroll
                    for (int k = 0; k < 4; ++k)
                        v += fast_tanh((float)yv[k] + sTW[h0 + k]) * sWa[h0 + k];
                }
            }
            v += __shfl_xor(v, 1);
            v += __shfl_xor(v, 2);
            if (li == 0 && l < sa) sLog[l] = v;
        }
        __syncthreads();
        if (wv == 0) {
            float x = (lane < sa) ? sLog[lane] : -3.4e38f;
            float m = x;
            #pragma unroll
            for (int off = 32; off > 0; off >>= 1) m = fmaxf(m, __shfl_xor(m, off));
            float e = (lane < sa) ? __expf(x - m) : 0.f;
            float s = e;
            #pragma unroll
            for (int off = 32; off > 0; off >>= 1) s += __shfl_xor(s, off);
            sAl[lane] = e / s;
        }
        __syncthreads();
        // Y-sum: wave wv covers h in [wv*64, wv*64+64); lane -> 4 h; l split over q
        {
            int h4 = wv*64 + lm*4;
            const _Float16* yb = Y16 + (size_t)u*L_*H_ + h4;
            float a0 = 0.f, a1 = 0.f, a2 = 0.f, a3 = 0.f;
            for (int l = q; l < sa; l += 4) {
                float al = sAl[l];
                half4_t yv = *(const half4_t*)(yb + (size_t)l*H_);
                a0 += al*(float)yv[0]; a1 += al*(float)yv[1];
                a2 += al*(float)yv[2]; a3 += al*(float)yv[3];
            }
            #pragma unroll
            for (int off = 16; off < 64; off <<= 1) {
                a0 += __shfl_xor(a0, off); a1 += __shfl_xor(a1, off);
                a2 += __shfl_xor(a2, off); a3 += __shfl_xor(a3, off);
            }
            if (q == 0) {
                half4_t o;
                o[0] = (_Float16)(a0 + fast_tanh(sW[256 + h4]));
                o[1] = (_Float16)(a1 + fast_tanh(sW[257 + h4]));
                o[2] = (_Float16)(a2 + fast_tanh(sW[258 + h4]));
                o[3] = (_Float16)(a3 + fast_tanh(sW[259 + h4]));
                *(half4_t*)(sR + h4) = o;
                if (t == sCap - 1)
                    *(half4_t*)(rL16 + (size_t)u*H_ + h4) = o;
            }
        }
    }
}

// ================= finals =================
__global__ __launch_bounds__(256) void k_final_gemm(const _Float16* __restrict__ rL16,
    const _Float16* __restrict__ h2, const _Float16* __restrict__ WfinT, float* __restrict__ ff)
{
    __shared__ _Float16 sA[64*40];
    __shared__ _Float16 sB[64*40];
    const int tid = threadIdx.x;
    const int n0 = blockIdx.x*64, m0 = blockIdx.y*64;
    const int lane = tid & 63, wv = tid >> 6;
    const int wm = (wv & 1)*32, wn = (wv >> 1)*32;
    const int q = lane >> 4, lm = lane & 15;
    const int am = tid >> 2, kg = (tid & 3)*8;
    const int row = m0 + am;
    const _Float16* bRow = WfinT + (size_t)(n0 + am)*512;
    floatx4 acc00 = {0.f,0.f,0.f,0.f}, acc01 = acc00, acc10 = acc00, acc11 = acc00;
    for (int ch = 0; ch < 16; ++ch) {
        const int k0 = ch*32;
        half8 av = (k0 < 256) ? *(const half8*)(rL16 + (size_t)row*H_ + k0 + kg)
                              : *(const half8*)(h2   + (size_t)row*H_ + (k0 - 256) + kg);
        half8 bv = *(const half8*)(bRow + k0 + kg);
        __syncthreads();
        *(half8*)(sA + am*40 + kg) = av;
        *(half8*)(sB + am*40 + kg) = bv;
        __syncthreads();
        half8 a0v = *(const half8*)(sA + (wm + lm)*40 + q*8);
        half8 a1v = *(const half8*)(sA + (wm + 16 + lm)*40 + q*8);
        half8 b0v = *(const half8*)(sB + (wn + lm)*40 + q*8);
        half8 b1v = *(const half8*)(sB + (wn + 16 + lm)*40 + q*8);
        acc00 = MFMA16(a0v, b0v, acc00); acc01 = MFMA16(a0v, b1v, acc01);
        acc10 = MFMA16(a1v, b0v, acc10); acc11 = MFMA16(a1v, b1v, acc11);
    }
    int rb = m0 + wm + q*4, col = n0 + wn + lm;
    #pragma unroll
    for (int r = 0; r < 4; ++r) {
        ff[(size_t)(rb + r)*H_ + col]           = acc00[r];
        ff[(size_t)(rb + r)*H_ + col + 16]      = acc01[r];
        ff[(size_t)(rb + 16 + r)*H_ + col]      = acc10[r];
        ff[(size_t)(rb + 16 + r)*H_ + col + 16] = acc11[r];
    }
}

__global__ __launch_bounds__(256) void k_final_out(const float* __restrict__ ff,
    const float* __restrict__ U, const float* __restrict__ b_out, float* __restrict__ out)
{
    __shared__ float sTh[16*256];
    __shared__ float sU[512];
    const int tid = threadIdx.x;
    const int b0 = blockIdx.x*16;
    sU[tid] = U[tid]; sU[256 + tid] = U[256 + tid];
    for (int idx = tid; idx < 16*256; idx += 256) {
        int r = idx >> 8, h = idx & 255;
        sTh[idx] = fast_tanh(ff[(size_t)(b0 + r)*256 + h]) + fast_tanh(ff[(size_t)(b0 + r + 512)*256 + h]);
    }
    __syncthreads();
    const int wv = tid >> 6, lane = tid & 63;
    for (int r = wv; r < 16; r += 4) {
        float p0 = 0.f, p1 = 0.f;
        #pragma unroll
        for (int k = 0; k < 4; ++k) {
            int h = lane*4 + k;
            float v = sTh[r*256 + h];
            p0 += v * sU[h*2];
            p1 += v * sU[h*2 + 1];
        }
        #pragma unroll
        for (int off = 32; off > 0; off >>= 1) { p0 += __shfl_down(p0, off); p1 += __shfl_down(p1, off); }
        if (lane == 0) {
            out[(b0 + r)*2]     = p0 + b_out[0];
            out[(b0 + r)*2 + 1] = p1 + b_out[1];
        }
    }
}

// ================= launcher (6 launches) =================
extern "C" void kernel_launch(void* const* d_in, const int* in_sizes, int n_in,
                              void* d_out, int out_size, void* d_ws, size_t ws_size,
                              hipStream_t stream)
{
    (void)in_sizes; (void)n_in; (void)out_size; (void)ws_size;
    const float* E    = (const float*)d_in[0];
    const float* Wx1  = (const float*)d_in[1];
    const float* Wh1  = (const float*)d_in[2];
    const float* b1   = (const float*)d_in[3];
    const float* Wx2  = (const float*)d_in[4];
    const float* Wh2  = (const float*)d_in[5];
    const float* b2   = (const float*)d_in[6];
    const float* W_y  = (const float*)d_in[7];
    const float* Wh_a = (const float*)d_in[8];
    const float* Wr_a = (const float*)d_in[9];
    const float* w_a  = (const float*)d_in[10];
    const float* Wt_a = (const float*)d_in[11];
    const float* Wp_a = (const float*)d_in[12];
    const float* Wxa  = (const float*)d_in[13];
    const float* U    = (const float*)d_in[14];
    const float* b_o  = (const float*)d_in[15];
    const int* in1 = (const int*)d_in[16];
    const int* in2 = (const int*)d_in[17];
    const int* s1  = (const int*)d_in[18];
    const int* s2  = (const int*)d_in[19];
    float* out = (float*)d_out;

    char* p = (char*)d_ws;
    auto alloc = [&](size_t bytes) { char* r = p; p += (bytes + 255) & ~(size_t)255; return r; };
    int*      bar   = (int*)     alloc(15360);                // 60*32 light slots * 2 ints
    _Float16* X16   = (_Float16*)alloc((size_t)BT*L_*KX*2);
    _Float16* Y16   = (_Float16*)alloc(2ull*BT*L_*H_*2);
    _Float16* WyY16 = (_Float16*)alloc((size_t)BT*L_*H_*2);
    _Float16* TH16  = (_Float16*)alloc((size_t)BT*L_*H_*2);
    _Float16* BcatT = (_Float16*)alloc(2ull*NG*KL*2);
    _Float16* AW    = (_Float16*)alloc(393216ull*2);
    _Float16* h16   = (_Float16*)alloc(4ull*BT*H_*2);
    _Float16* rL16  = (_Float16*)alloc((size_t)BT*H_*2);
    float*    ff    = (float*)   alloc((size_t)BT*H_*4);

    _Float16* WfinT = AW + 262144;
    _Float16* h2    = h16 + 2ull*BT*H_;     // set1, parity 0 (after t=59)

    k_prep<<<512, 256, 0, stream>>>(E, Wx1, Wh1, Wx2, Wh2, W_y, Wh_a, Wr_a, Wt_a,
                                    Wp_a, Wxa, in1, in2, X16, BcatT, AW, bar);
    k_lstm<<<512, 256, 0, stream>>>(X16, BcatT, b1, b2, s1, s2, Y16, h16, bar);
    k_wyyth<<<512, 256, 0, stream>>>(Y16, AW, WyY16, TH16);
    k_attn<<<1024, 256, 0, stream>>>(Y16, WyY16, TH16, AW, w_a, rL16, s1, s2);
    k_final_gemm<<<dim3(4, 16), 256, 0, stream>>>(rL16, h2, WfinT, ff);
    k_final_out<<<32, 256, 0, stream>>>(ff, U, b_o, out);
}

// Round 8
// 2708.994 us; speedup vs baseline: 1.1698x; 1.1698x over previous
//
#include <hip/hip_runtime.h>
#include <cstdint>
#include <cstddef>

#define B_  512
#define L_  60
#define D_  300
#define H_  256
#define BT  1024
#define KX  320
#define KL  576
#define NG  1024

typedef _Float16 half8   __attribute__((ext_vector_type(8)));
typedef _Float16 half4_t __attribute__((ext_vector_type(4)));
typedef float    floatx4 __attribute__((ext_vector_type(4)));

__device__ __forceinline__ float fast_tanh(float x){ float e = __expf(2.f*x); return 1.f - 2.f/(e + 1.f); }
__device__ __forceinline__ float sigm(float x){ return 1.f/(1.f + __expf(-x)); }

#define MFMA16(a,b,c) __builtin_amdgcn_mfma_f32_16x16x32_f16(a,b,c,0,0,0)

// light barrier: ordering only; h data travels via agent-scope (IF$) atomics.
__device__ __forceinline__ void sync_group(int* slot, int nexp)
{
    __syncthreads();
    if (threadIdx.x == 0) {
        int prev = __hip_atomic_fetch_add(slot, 1, __ATOMIC_RELAXED, __HIP_MEMORY_SCOPE_AGENT);
        if (prev == nexp - 1) {
            __hip_atomic_store(slot + 1, 1, __ATOMIC_RELAXED, __HIP_MEMORY_SCOPE_AGENT);
        } else {
            while (!__hip_atomic_load(slot + 1, __ATOMIC_RELAXED, __HIP_MEMORY_SCOPE_AGENT))
                __builtin_amdgcn_s_sleep(1);
        }
    }
    __syncthreads();
}

// ================= k_prep: gather X, transpose weights, zero barriers =================
__global__ __launch_bounds__(256) void k_prep(const float* __restrict__ E,
    const float* __restrict__ Wx1, const float* __restrict__ Wh1,
    const float* __restrict__ Wx2, const float* __restrict__ Wh2,
    const float* __restrict__ W_y, const float* __restrict__ Wh_a, const float* __restrict__ Wr_a,
    const float* __restrict__ Wt_a, const float* __restrict__ Wp_a, const float* __restrict__ Wxa,
    const int* __restrict__ in1, const int* __restrict__ in2,
    _Float16* __restrict__ X16, _Float16* __restrict__ BcatT, _Float16* __restrict__ AW,
    int* __restrict__ bar)
{
    const int tid = threadIdx.x, bid = blockIdx.x;
    int g0 = bid*256 + tid;
    if (g0 < 3840) bar[g0] = 0;

    for (int it = 0; it < 19; ++it) {
        int gid = it*131072 + g0;
        if (gid < 2457600) {
            int row = gid / (L_*40);
            int rem = gid - row*(L_*40);
            int t  = rem / 40;
            int ch = rem - t*40;
            int k0 = ch*8;
            int tok = (row < B_) ? in1[row*L_ + t] : in2[(row - B_)*L_ + t];
            const float* src = E + (size_t)tok*D_ + k0;
            half8 o;
            #pragma unroll
            for (int k = 0; k < 8; ++k) o[k] = (_Float16)0.f;
            if (k0 + 8 <= D_) {
                float4 a = *(const float4*)(src);
                float4 b = *(const float4*)(src + 4);
                o[0]=(_Float16)a.x; o[1]=(_Float16)a.y; o[2]=(_Float16)a.z; o[3]=(_Float16)a.w;
                o[4]=(_Float16)b.x; o[5]=(_Float16)b.y; o[6]=(_Float16)b.z; o[7]=(_Float16)b.w;
            } else if (k0 < D_) {
                float4 a = *(const float4*)(src);
                o[0]=(_Float16)a.x; o[1]=(_Float16)a.y; o[2]=(_Float16)a.z; o[3]=(_Float16)a.w;
            }
            *(half8*)(X16 + ((size_t)row*L_ + t)*KX + k0) = o;
        }
    }
    for (int it = 0; it < 9; ++it) {
        int idx = it*131072 + g0;                 // 9*131072 == 2*KL*NG exactly
        int set = (idx >= KL*NG) ? 1 : 0;
        int rem = idx - set*(KL*NG);
        int k = rem >> 10, n = rem & 1023;
        const float* Wx = set ? Wx2 : Wx1;
        const float* Wh = set ? Wh2 : Wh1;
        float v = 0.f;
        if (k < D_)       v = Wx[k*NG + n];
        else if (k >= KX) v = Wh[(k - KX)*NG + n];
        BcatT[((size_t)set*NG + n)*KL + k] = (_Float16)v;
    }
    for (int it = 0; it < 4; ++it) {
        int idx = it*131072 + g0;
        if (idx < 458752) {
            float v; int dst;
            if (idx < 65536) {
                int k = idx >> 8, n = idx & 255;
                v = W_y[k*256 + n];
                dst = n*256 + k;
            } else if (idx < 131072) {
                int j = idx - 65536; int k = j >> 8, n = j & 255;
                v = Wh_a[k*256 + n];
                dst = 65536 + n*256 + k;
            } else if (idx < 262144) {
                int j = idx - 131072; int n = j >> 8, k = j & 255;
                v = (n < 256) ? Wr_a[k*256 + n] : Wt_a[k*256 + (n - 256)];
                dst = 131072 + n*256 + k;
            } else {
                int j = idx - 262144; int n = j >> 9, k = j & 511;
                v = (k < 256) ? Wp_a[k*256 + n] : Wxa[(k - 256)*256 + n];
                dst = 262144 + n*512 + k;
            }
            AW[dst] = (_Float16)v;
        }
    }
}

// ================= k_lstm: persistent, 512 blocks, 59 light group barriers =================
__global__ __launch_bounds__(256, 2) void k_lstm(
    const _Float16* __restrict__ X16, const _Float16* __restrict__ BcatT,
    const float* __restrict__ b1, const float* __restrict__ b2,
    const int* __restrict__ s1, const int* __restrict__ s2,
    _Float16* __restrict__ Y16, _Float16* __restrict__ h16, int* __restrict__ bar)
{
    __shared__ float sG[2][64][65];            // aliases sA
    _Float16* sA = (_Float16*)sG;

    const int tid = threadIdx.x, bid = blockIdx.x;
    const int lane = tid & 63, wv = tid >> 6;
    const int q = lane >> 4, lm = lane & 15;
    const int ht = bid & 15, mt = bid >> 4;
    const int set = mt >> 4;
    const int m0 = mt*64;
    const int kh = wv >> 1;
    const int wn = (wv & 1)*32;
    const int cb = wn >> 4;

    half8 bfr[9][2];
    #pragma unroll
    for (int ch = 0; ch < 9; ++ch)
        #pragma unroll
        for (int ti = 0; ti < 2; ++ti)
            bfr[ch][ti] = *(const half8*)(BcatT +
                ((size_t)set*NG + (cb+ti)*256 + ht*16 + lm)*KL + kh*288 + ch*32 + q*8);

    const int amA = tid >> 2, kgA = (tid & 3)*8;
    const int rsA = (m0 + amA) & 1023;
    const int xrowA = set ? ((rsA + 512) & 1023) : rsA;

    const float* bias = set ? b2 : b1;
    const int pc = tid & 7;
    const int eh = ht*16 + pc*2;
    float bI[2], bJ[2], bF[2], bO[2];
    #pragma unroll
    for (int j = 0; j < 2; ++j) {
        bI[j] = bias[eh + j]; bJ[j] = bias[256 + eh + j];
        bF[j] = bias[512 + eh + j]; bO[j] = bias[768 + eh + j];
    }
    int esl[2]; float c_st[2][2], h_st[2][2];
    #pragma unroll
    for (int rp = 0; rp < 2; ++rp) {
        int rs = (m0 + (tid >> 3) + rp*32) & 1023;
        esl[rp] = (set == 0) ? ((rs < B_) ? s1[rs] : s2[rs - B_])
                             : ((rs < B_) ? s2[rs] : s1[rs - B_]);
        c_st[rp][0] = 0.f; c_st[rp][1] = 0.f;
        h_st[rp][0] = 0.f; h_st[rp][1] = 0.f;
    }

    half8 zero8;
    #pragma unroll
    for (int k = 0; k < 8; ++k) zero8[k] = (_Float16)0.f;

    for (int t = 0; t < L_; ++t) {
        const int p_in = t & 1, p_out = (t + 1) & 1;
        const _Float16* hin  = h16 + (size_t)(set*2 + p_in)*BT*H_;
        _Float16*       hout = h16 + (size_t)(set*2 + p_out)*BT*H_;
        const _Float16* aX = X16 + ((size_t)xrowA*L_ + t)*KX;
        const _Float16* aH = hin + (size_t)rsA*H_;

        half8 hreg[8];
        if (t > 0) {
            #pragma unroll
            for (int j = 0; j < 8; ++j) {
                union { unsigned long long u[2]; half8 v; } cv;
                const _Float16* hp = aH + j*32 + kgA;
                cv.u[0] = __hip_atomic_load((const unsigned long long*)(hp),
                                            __ATOMIC_RELAXED, __HIP_MEMORY_SCOPE_AGENT);
                cv.u[1] = __hip_atomic_load((const unsigned long long*)(hp + 4),
                                            __ATOMIC_RELAXED, __HIP_MEMORY_SCOPE_AGENT);
                hreg[j] = cv.v;
            }
        } else {
            #pragma unroll
            for (int j = 0; j < 8; ++j) hreg[j] = zero8;
        }

        floatx4 acc[4][2];
        #pragma unroll
        for (int mi = 0; mi < 4; ++mi)
            #pragma unroll
            for (int ti = 0; ti < 2; ++ti) acc[mi][ti] = (floatx4){0.f,0.f,0.f,0.f};

        half8 av0 = *(const half8*)(aX + kgA);
        half8 av1f = *(const half8*)(aX + 288 + kgA);

        #pragma unroll
        for (int i = 0; i < 9; ++i) {
            __syncthreads();
            *(half8*)(sA + (     amA)*40 + kgA) = av0;
            *(half8*)(sA + (64 + amA)*40 + kgA) = (i == 0) ? av1f : hreg[i-1];
            __syncthreads();
            if (i < 8) av0 = *(const half8*)(aX + (i+1)*32 + kgA);
            half8 af[4];
            #pragma unroll
            for (int mi = 0; mi < 4; ++mi)
                af[mi] = *(const half8*)(sA + (kh*64 + mi*16 + lm)*40 + q*8);
            #pragma unroll
            for (int mi = 0; mi < 4; ++mi) {
                acc[mi][0] = MFMA16(af[mi], bfr[i][0], acc[mi][0]);
                acc[mi][1] = MFMA16(af[mi], bfr[i][1], acc[mi][1]);
            }
        }

        __syncthreads();
        #pragma unroll
        for (int mi = 0; mi < 4; ++mi)
            #pragma unroll
            for (int ti = 0; ti < 2; ++ti)
                #pragma unroll
                for (int r = 0; r < 4; ++r)
                    sG[kh][mi*16 + q*4 + r][wn + ti*16 + lm] = acc[mi][ti][r];
        __syncthreads();

        #pragma unroll
        for (int rp = 0; rp < 2; ++rp) {
            int row = (tid >> 3) + rp*32;
            int gr = m0 + row;
            int rs = gr & 1023;
            bool act = (t < esl[rp]);
            union { _Float16 h[2]; uint32_t u; } hp, yp;
            #pragma unroll
            for (int j = 0; j < 2; ++j) {
                int hh = pc*2 + j;
                float gi = sG[0][row][     hh] + sG[1][row][     hh] + bI[j];
                float gj = sG[0][row][16 + hh] + sG[1][row][16 + hh] + bJ[j];
                float gf = sG[0][row][32 + hh] + sG[1][row][32 + hh] + bF[j];
                float go = sG[0][row][48 + hh] + sG[1][row][48 + hh] + bO[j];
                float c_new = c_st[rp][j]*sigm(gf + 1.f) + sigm(gi)*fast_tanh(gj);
                float h_new = fast_tanh(c_new)*sigm(go);
                if (act) { c_st[rp][j] = c_new; h_st[rp][j] = h_new; }
                hp.h[j] = (_Float16)h_st[rp][j];
                yp.h[j] = act ? (_Float16)h_new : (_Float16)0.f;
            }
            __hip_atomic_store((uint32_t*)(hout + (size_t)rs*H_ + eh), hp.u,
                               __ATOMIC_RELAXED, __HIP_MEMORY_SCOPE_AGENT);
            *(uint32_t*)(Y16 + ((size_t)gr*L_ + t)*H_ + eh) = yp.u;
        }
        if (t < L_ - 1)
            sync_group(bar + (t*32 + mt)*2, 16);
    }
}

// ================= k_wyyth: WyY (z=0) / TH (z=1), B cached in LDS =================
__global__ __launch_bounds__(256) void k_wyyth(const _Float16* __restrict__ Y16,
    const _Float16* __restrict__ AW, _Float16* __restrict__ WyY16, _Float16* __restrict__ TH16)
{
    __shared__ _Float16 sB[64*264];
    const int tid = threadIdx.x, bid = blockIdx.x;
    const int lane = tid & 63, wv = tid >> 6;
    const int q = lane >> 4, lm = lane & 15;
    const int slot = bid & 7;
    const int z = slot >> 2, nt = slot & 3;
    const int n0 = nt*64;
    {
        int rowB = tid >> 2;
        int kb = (tid & 3)*64;
        #pragma unroll
        for (int s = 0; s < 8; ++s)
            *(half8*)(sB + rowB*264 + kb + s*8) =
                *(const half8*)(AW + (size_t)z*65536 + (size_t)(n0 + rowB)*H_ + kb + s*8);
    }
    __syncthreads();
    const _Float16* Ybase = Y16 + (size_t)z*((size_t)BT*L_*H_);
    _Float16* dst = z ? TH16 : WyY16;
    for (int mi_ = 0; mi_ < 15; ++mi_) {
        int m0w = ((bid >> 3) + mi_*64)*64;
        floatx4 acc[4];
        #pragma unroll
        for (int ti = 0; ti < 4; ++ti) acc[ti] = (floatx4){0.f,0.f,0.f,0.f};
        const _Float16* aRow = Ybase + (size_t)(m0w + wv*16 + lm)*H_ + q*8;
        #pragma unroll
        for (int ch = 0; ch < 8; ++ch) {
            half8 a = *(const half8*)(aRow + ch*32);
            #pragma unroll
            for (int ti = 0; ti < 4; ++ti) {
                half8 b = *(const half8*)(sB + (ti*16 + lm)*264 + ch*32 + q*8);
                acc[ti] = MFMA16(a, b, acc[ti]);
            }
        }
        #pragma unroll
        for (int ti = 0; ti < 4; ++ti)
            #pragma unroll
            for (int r = 0; r < 4; ++r)
                dst[(size_t)(m0w + wv*16 + q*4 + r)*H_ + n0 + ti*16 + lm] = (_Float16)acc[ti][r];
    }
}

// ================= k_attn: 256 blocks x 4 rows, weights in registers =================
// Wave wv owns cols [wv*128, wv*128+128) of [Wr|Wt] as 64 register b-fragments
// (loaded once), and owns row wv for logits/softmax/Y-sum. Per-step weight
// memory traffic: ZERO. Logit loads half8-widened (full-line quads).
__global__ __launch_bounds__(256, 1) void k_attn(
    const _Float16* __restrict__ Y16, const _Float16* __restrict__ WyY16,
    const _Float16* __restrict__ TH16, const _Float16* __restrict__ AW,
    const float* __restrict__ w_a, _Float16* __restrict__ rL16,
    const int* __restrict__ s1, const int* __restrict__ s2)
{
    __shared__ _Float16 sR[16*264];    // rows 0-3 live (block's 4 r vectors)
    __shared__ float sW[4*520];
    __shared__ float sTW[4*264];
    __shared__ float sLog[4*64];
    __shared__ float sAl[4*64];
    __shared__ float sWa[256];
    __shared__ int   sCap[4], sAtt[4];

    const int tid = threadIdx.x, u0 = blockIdx.x*4;
    const int lane = tid & 63, wv = tid >> 6;
    const int q = lane >> 4, lm = lane & 15;

    if (tid < 4) {
        int u = u0 + tid;
        if (u < B_) { sCap[tid] = s2[u];      sAtt[tid] = s1[u]; }
        else        { sCap[tid] = s1[u - B_]; sAtt[tid] = s2[u - B_]; }
    }
    sWa[tid] = w_a[tid];
    for (int i = tid; i < 16*264; i += 256) sR[i] = (_Float16)0.f;
    __syncthreads();
    const int mcap = max(max(sCap[0], sCap[1]), max(sCap[2], sCap[3]));

    // ---- weights once into registers: col = wv*128 + ti*16 + lm, k = ch*32 + q*8
    const _Float16* WrtT = AW + 131072;
    half8 bw[8][8];
    #pragma unroll
    for (int ti = 0; ti < 8; ++ti)
        #pragma unroll
        for (int ch = 0; ch < 8; ++ch)
            bw[ti][ch] = *(const half8*)(WrtT + (size_t)(wv*128 + ti*16 + lm)*256 + ch*32 + q*8);

    const int row = wv;
    const int u = u0 + row;
    const int sa = sAtt[row];
    const int myCap = sCap[row];
    const int lsub = lane >> 2, li = lane & 3;

    for (int t = 0; t < mcap; ++t) {
        __syncthreads();   // sR stable from previous step
        // ---- rGEMM: 64 reg-weight MFMA -> all 4 rows x this wave's 128 cols
        if (t > 0) {
            floatx4 acc[8];
            #pragma unroll
            for (int i = 0; i < 8; ++i) acc[i] = (floatx4){0.f,0.f,0.f,0.f};
            #pragma unroll
            for (int ch = 0; ch < 8; ++ch) {
                half8 a = *(const half8*)(sR + lm*264 + ch*32 + q*8);
                #pragma unroll
                for (int ti = 0; ti < 8; ++ti)
                    acc[ti] = MFMA16(a, bw[ti][ch], acc[ti]);
            }
            if (q == 0) {
                #pragma unroll
                for (int ti = 0; ti < 8; ++ti)
                    #pragma unroll
                    for (int r = 0; r < 4; ++r)
                        sW[r*520 + wv*128 + ti*16 + lm] = acc[ti][r];
            }
        } else {
            for (int i = tid; i < 4*520; i += 256) sW[i] = 0.f;
        }
        __syncthreads();
        // ---- sTW = TH[u][t] + rWr   (half8 loads, 128 threads)
        if (tid < 128) {
            int rw = tid >> 5, hb = (tid & 31)*8;
            half8 th = *(const half8*)(TH16 + ((size_t)(u0 + rw)*L_ + t)*H_ + hb);
            #pragma unroll
            for (int k = 0; k < 8; ++k)
                sTW[rw*264 + hb + k] = (float)th[k] + sW[rw*520 + hb + k];
        }
        __syncthreads();

        if (t < myCap) {
            // ---- logits: 16 l-slots/pass, quad li covers h via half8 (full lines)
            for (int lb = 0; lb*16 < sa; ++lb) {
                int l = lb*16 + lsub;
                float v = 0.f;
                if (l < sa) {
                    const _Float16* wy = WyY16 + ((size_t)u*L_ + l)*H_;
                    #pragma unroll
                    for (int j = 0; j < 8; ++j) {
                        int h0 = j*32 + li*8;
                        half8 yv = *(const half8*)(wy + h0);
                        #pragma unroll
                        for (int k = 0; k < 8; ++k)
                            v += fast_tanh((float)yv[k] + sTW[row*264 + h0 + k]) * sWa[h0 + k];
                    }
                }
                v += __shfl_xor(v, 1);
                v += __shfl_xor(v, 2);
                if (li == 0 && l < sa) sLog[row*64 + l] = v;
            }
            // ---- softmax (wave-private)
            {
                float x = (lane < sa) ? sLog[row*64 + lane] : -3.4e38f;
                float m = x;
                #pragma unroll
                for (int off = 32; off > 0; off >>= 1) m = fmaxf(m, __shfl_xor(m, off));
                float e = (lane < sa) ? __expf(x - m) : 0.f;
                float s = e;
                #pragma unroll
                for (int off = 32; off > 0; off >>= 1) s += __shfl_xor(s, off);
                sAl[row*64 + lane] = e / s;
            }
            // ---- Y-sum: lane (q,lm): h = lm*16..+15, l strided by q
            {
                float ys[16];
                #pragma unroll
                for (int k = 0; k < 16; ++k) ys[k] = 0.f;
                for (int l = q; l < sa; l += 4) {
                    float al = sAl[row*64 + l];
                    const _Float16* yp = Y16 + ((size_t)u*L_ + l)*H_ + lm*16;
                    half8 y0 = *(const half8*)(yp);
                    half8 y1 = *(const half8*)(yp + 8);
                    #pragma unroll
                    for (int k = 0; k < 8; ++k) {
                        ys[k]     += al*(float)y0[k];
                        ys[8 + k] += al*(float)y1[k];
                    }
                }
                #pragma unroll
                for (int k = 0; k < 16; ++k) {
                    ys[k] += __shfl_xor(ys[k], 16);
                    ys[k] += __shfl_xor(ys[k], 32);
                }
                if (q == 0) {
                    half8 o0, o1;
                    #pragma unroll
                    for (int k = 0; k < 8; ++k) {
                        o0[k] = (_Float16)(ys[k]     + fast_tanh(sW[row*520 + 256 + lm*16 + k]));
                        o1[k] = (_Float16)(ys[8 + k] + fast_tanh(sW[row*520 + 256 + lm*16 + 8 + k]));
                    }
                    *(half8*)(sR + row*264 + lm*16)     = o0;
                    *(half8*)(sR + row*264 + lm*16 + 8) = o1;
                    if (t == myCap - 1) {
                        *(half8*)(rL16 + (size_t)u*H_ + lm*16)     = o0;
                        *(half8*)(rL16 + (size_t)u*H_ + lm*16 + 8) = o1;
                    }
                }
            }
        }
    }
}

// ================= finals =================
__global__ __launch_bounds__(256) void k_final_gemm(const _Float16* __restrict__ rL16,
    const _Float16* __restrict__ h2, const _Float16* __restrict__ WfinT, float* __restrict__ ff)
{
    __shared__ _Float16 sA[64*40];
    __shared__ _Float16 sB[64*40];
    const int tid = threadIdx.x;
    const int n0 = blockIdx.x*64, m0 = blockIdx.y*64;
    const int lane = tid & 63, wv = tid >> 6;
    const int wm = (wv & 1)*32, wn = (wv >> 1)*32;
    const int q = lane >> 4, lm = lane & 15;
    const int am = tid >> 2, kg = (tid & 3)*8;
    const int row = m0 + am;
    const _Float16* bRow = WfinT + (size_t)(n0 + am)*512;
    floatx4 acc00 = {0.f,0.f,0.f,0.f}, acc01 = acc00, acc10 = acc00, acc11 = acc00;
    for (int ch = 0; ch < 16; ++ch) {
        const int k0 = ch*32;
        half8 av = (k0 < 256) ? *(const half8*)(rL16 + (size_t)row*H_ + k0 + kg)
                              : *(const half8*)(h2   + (size_t)row*H_ + (k0 - 256) + kg);
        half8 bv = *(const half8*)(bRow + k0 + kg);
        __syncthreads();
        *(half8*)(sA + am*40 + kg) = av;
        *(half8*)(sB + am*40 + kg) = bv;
        __syncthreads();
        half8 a0v = *(const half8*)(sA + (wm + lm)*40 + q*8);
        half8 a1v = *(const half8*)(sA + (wm + 16 + lm)*40 + q*8);
        half8 b0v = *(const half8*)(sB + (wn + lm)*40 + q*8);
        half8 b1v = *(const half8*)(sB + (wn + 16 + lm)*40 + q*8);
        acc00 = MFMA16(a0v, b0v, acc00); acc01 = MFMA16(a0v, b1v, acc01);
        acc10 = MFMA16(a1v, b0v, acc10); acc11 = MFMA16(a1v, b1v, acc11);
    }
    int rb = m0 + wm + q*4, col = n0 + wn + lm;
    #pragma unroll
    for (int r = 0; r < 4; ++r) {
        ff[(size_t)(rb + r)*H_ + col]           = acc00[r];
        ff[(size_t)(rb + r)*H_ + col + 16]      = acc01[r];
        ff[(size_t)(rb + 16 + r)*H_ + col]      = acc10[r];
        ff[(size_t)(rb + 16 + r)*H_ + col + 16] = acc11[r];
    }
}

__global__ __launch_bounds__(256) void k_final_out(const float* __restrict__ ff,
    const float* __restrict__ U, const float* __restrict__ b_out, float* __restrict__ out)
{
    __shared__ float sTh[16*256];
    __shared__ float sU[512];
    const int tid = threadIdx.x;
    const int b0 = blockIdx.x*16;
    sU[tid] = U[tid]; sU[256 + tid] = U[256 + tid];
    for (int idx = tid; idx < 16*256; idx += 256) {
        int r = idx >> 8, h = idx & 255;
        sTh[idx] = fast_tanh(ff[(size_t)(b0 + r)*256 + h]) + fast_tanh(ff[(size_t)(b0 + r + 512)*256 + h]);
    }
    __syncthreads();
    const int wv = tid >> 6, lane = tid & 63;
    for (int r = wv; r < 16; r += 4) {
        float p0 = 0.f, p1 = 0.f;
        #pragma unroll
        for (int k = 0; k < 4; ++k) {
            int h = lane*4 + k;
            float v = sTh[r*256 + h];
            p0 += v * sU[h*2];
            p1 += v * sU[h*2 + 1];
        }
        #pragma unroll
        for (int off = 32; off > 0; off >>= 1) { p0 += __shfl_down(p0, off); p1 += __shfl_down(p1, off); }
        if (lane == 0) {
            out[(b0 + r)*2]     = p0 + b_out[0];
            out[(b0 + r)*2 + 1] = p1 + b_out[1];
        }
    }
}

// ================= launcher (6 launches) =================
extern "C" void kernel_launch(void* const* d_in, const int* in_sizes, int n_in,
                              void* d_out, int out_size, void* d_ws, size_t ws_size,
                              hipStream_t stream)
{
    (void)in_sizes; (void)n_in; (void)out_size; (void)ws_size;
    const float* E    = (const float*)d_in[0];
    const float* Wx1  = (const float*)d_in[1];
    const float* Wh1  = (const float*)d_in[2];
    const float* b1   = (const float*)d_in[3];
    const float* Wx2  = (const float*)d_in[4];
    const float* Wh2  = (const float*)d_in[5];
    const float* b2   = (const float*)d_in[6];
    const float* W_y  = (const float*)d_in[7];
    const float* Wh_a = (const float*)d_in[8];
    const float* Wr_a = (const float*)d_in[9];
    const float* w_a  = (const float*)d_in[10];
    const float* Wt_a = (const float*)d_in[11];
    const float* Wp_a = (const float*)d_in[12];
    const float* Wxa  = (const float*)d_in[13];
    const float* U    = (const float*)d_in[14];
    const float* b_o  = (const float*)d_in[15];
    const int* in1 = (const int*)d_in[16];
    const int* in2 = (const int*)d_in[17];
    const int* s1  = (const int*)d_in[18];
    const int* s2  = (const int*)d_in[19];
    float* out = (float*)d_out;

    char* p = (char*)d_ws;
    auto alloc = [&](size_t bytes) { char* r = p; p += (bytes + 255) & ~(size_t)255; return r; };
    int*      bar   = (int*)     alloc(15360);
    _Float16* X16   = (_Float16*)alloc((size_t)BT*L_*KX*2);
    _Float16* Y16   = (_Float16*)alloc(2ull*BT*L_*H_*2);
    _Float16* WyY16 = (_Float16*)alloc((size_t)BT*L_*H_*2);
    _Float16* TH16  = (_Float16*)alloc((size_t)BT*L_*H_*2);
    _Float16* BcatT = (_Float16*)alloc(2ull*NG*KL*2);
    _Float16* AW    = (_Float16*)alloc(393216ull*2);
    _Float16* h16   = (_Float16*)alloc(4ull*BT*H_*2);
    _Float16* rL16  = (_Float16*)alloc((size_t)BT*H_*2);
    float*    ff    = (float*)   alloc((size_t)BT*H_*4);

    _Float16* WfinT = AW + 262144;
    _Float16* h2    = h16 + 2ull*BT*H_;

    k_prep<<<512, 256, 0, stream>>>(E, Wx1, Wh1, Wx2, Wh2, W_y, Wh_a, Wr_a, Wt_a,
                                    Wp_a, Wxa, in1, in2, X16, BcatT, AW, bar);
    k_lstm<<<512, 256, 0, stream>>>(X16, BcatT, b1, b2, s1, s2, Y16, h16, bar);
    k_wyyth<<<512, 256, 0, stream>>>(Y16, AW, WyY16, TH16);
    k_attn<<<256, 256, 0, stream>>>(Y16, WyY16, TH16, AW, w_a, rL16, s1, s2);
    k_final_gemm<<<dim3(4, 16), 256, 0, stream>>>(rL16, h2, WfinT, ff);
    k_final_out<<<32, 256, 0, stream>>>(ff, U, b_o, out);
}